// Round 3
// baseline (553.245 us; speedup 1.0000x reference)
//
#include <hip/hip_runtime.h>
#include <hip/hip_bf16.h>

typedef unsigned short u16;
typedef unsigned int u32;
typedef __attribute__((ext_vector_type(8))) short short8;
typedef __attribute__((ext_vector_type(8))) unsigned short ushort8;
typedef __attribute__((ext_vector_type(4))) float f32x4;

#define AS1 __attribute__((address_space(1)))
#define AS3 __attribute__((address_space(3)))

#define Bb_ 128
#define Nn_ 512
#define Cc_ 512
#define NK_ 515

__device__ __forceinline__ u16 f2bf(float f) {
    union { float f; u32 i; } t; t.f = f;
    u32 x = t.i;
    u32 r = (x + 0x7fffu + ((x >> 16) & 1u)) >> 16;  // round-nearest-even
    return (u16)r;
}

// ---------------------------------------------------------------------------
// Kernel 1 (fused prep): per (b,n) row of fp32 query:
//   qbf[row][c] = bf16(q[row][c])
//   dw[row][j]  = sum_c q[row][c]*W[c][j] + b_lin[j]   (fp32, j=0..2)
// ---------------------------------------------------------------------------
#define ROWS_PER_WAVE 32
__global__ void prep_kernel(const float* __restrict__ q, const float* __restrict__ W,
                            const float* __restrict__ bl,
                            u16* __restrict__ qbf, float* __restrict__ dw) {
    __shared__ float wc[3][512];
    int tid = threadIdx.x;
    for (int idx = tid; idx < 3 * 512; idx += 256) {
        int j = idx >> 9, c = idx & 511;
        wc[j][c] = W[c * NK_ + j];
    }
    __syncthreads();

    int w = tid >> 6, l = tid & 63;
    int c0 = l * 8;
    float w0[8], w1[8], w2[8];
#pragma unroll
    for (int e = 0; e < 8; e++) {
        w0[e] = wc[0][c0 + e];
        w1[e] = wc[1][c0 + e];
        w2[e] = wc[2][c0 + e];
    }
    float bl0 = bl[0], bl1 = bl[1], bl2 = bl[2];

    size_t row0 = (size_t)blockIdx.x * (4 * ROWS_PER_WAVE) + (size_t)w * ROWS_PER_WAVE;
#pragma unroll 2
    for (int rr = 0; rr < ROWS_PER_WAVE; rr++) {
        size_t row = row0 + rr;
        const float* qr = q + row * Cc_;
        f32x4 x0 = *(const f32x4*)(qr + c0);
        f32x4 x1 = *(const f32x4*)(qr + c0 + 4);
        float xf[8] = {x0[0], x0[1], x0[2], x0[3], x1[0], x1[1], x1[2], x1[3]};
        ushort8 y;
        float s0 = 0.f, s1 = 0.f, s2 = 0.f;
#pragma unroll
        for (int e = 0; e < 8; e++) {
            float qf = xf[e];
            y[e] = f2bf(qf);
            s0 += qf * w0[e];
            s1 += qf * w1[e];
            s2 += qf * w2[e];
        }
        *(ushort8*)(qbf + row * Cc_ + c0) = y;
#pragma unroll
        for (int off = 32; off > 0; off >>= 1) {
            s0 += __shfl_xor(s0, off);
            s1 += __shfl_xor(s1, off);
            s2 += __shfl_xor(s2, off);
        }
        if (l == 0) {
            dw[row * 3 + 0] = s0 + bl0;
            dw[row * 3 + 1] = s1 + bl1;
            dw[row * 3 + 2] = s2 + bl2;
        }
    }
}

// ---------------------------------------------------------------------------
// Kernel 2: WT[n][c] = bf16(W_lin[c][n+3])   (512x512)
// ---------------------------------------------------------------------------
__global__ void wt_kernel(const float* __restrict__ W, u16* __restrict__ WT) {
    int n = blockIdx.y;
    int c = blockIdx.x * 256 + threadIdx.x;
    WT[n * Cc_ + c] = f2bf(W[c * NK_ + n + 3]);
}

// ---------------------------------------------------------------------------
// Kernel 3: depthT[b][c][n] = bf16(relu(dw0*v[c-1] + dw1*v[c] + dw2*v[c+1]))
// ---------------------------------------------------------------------------
__global__ void depthT_kernel(const float* __restrict__ val, const float* __restrict__ dw,
                              u16* __restrict__ dT) {
    __shared__ float vt[64][67];
    __shared__ float dws[64][3];
    int b = blockIdx.z;
    int c0 = blockIdx.x * 64;
    int n0 = blockIdx.y * 64;
    int tid = threadIdx.x;

    const float* vbase = val + ((size_t)b * Nn_ + n0) * Cc_;
    for (int idx = tid; idx < 64 * 66; idx += 256) {
        int r = idx / 66, cc = idx % 66;
        int c = c0 - 1 + cc;
        float x = 0.f;
        if (c >= 0 && c < Cc_) x = vbase[(size_t)r * Cc_ + c];
        vt[r][cc] = x;
    }
    if (tid < 192) {
        int r = tid / 3, j = tid % 3;
        dws[r][j] = dw[((size_t)b * Nn_ + n0 + r) * 3 + j];
    }
    __syncthreads();

    int nn = tid & 63;
    int ccb = tid >> 6;
    u16* out = dT + ((size_t)b * Cc_ + c0) * Nn_ + n0;
    float d0 = dws[nn][0], d1 = dws[nn][1], d2 = dws[nn][2];
#pragma unroll
    for (int p = 0; p < 16; p++) {
        int cc = ccb + p * 4;
        float x = d0 * vt[nn][cc] + d1 * vt[nn][cc + 1] + d2 * vt[nn][cc + 2];
        x = x > 0.f ? x : 0.f;
        out[(size_t)cc * Nn_ + nn] = f2bf(x);
    }
}

// ---------------------------------------------------------------------------
// Kernel 4: GEMM1: pw[b][m][n] = sum_c qbf[b][m][c] * WT[n][c] + b_lin[n+3]
// 128x128 tile, BK=32, 4 waves of 64x64. Double-buffered prefetch
// + bijective batch-contiguous XCD swizzle. (unchanged from round 2)
// ---------------------------------------------------------------------------
__global__ __launch_bounds__(256, 2) void gemm1(const u16* __restrict__ A,
                                                const u16* __restrict__ Bt,
                                                u16* __restrict__ Out,
                                                const float* __restrict__ bias) {
    __shared__ __align__(16) u16 lA[2][128 * 32];
    __shared__ __align__(16) u16 lB[2][128 * 32];

    // grid = 2048 = 8 XCDs x 256 slots; 16 consecutive slots = one batch
    int wg = blockIdx.x;
    int xcd = wg & 7, slot = wg >> 3;
    int b = xcd * 16 + (slot >> 4);
    int tile = slot & 15;
    int tileM = tile >> 2, tileN = tile & 3;

    const u16* Ab = A + ((size_t)b * Nn_ + (size_t)tileM * 128) * Cc_;
    const u16* Bb = Bt + (size_t)tileN * 128 * Cc_;   // WT shared by all batches

    int tid = threadIdx.x, w = tid >> 6, l = tid & 63;
    int rsub = l >> 2;      // 0..15
    int csub = l & 3;       // 0..3
    int wm = w & 1, wn = w >> 1;
    int m_off = wm * 64, n_off = wn * 64;
    int row_l = l & 15, quad = l >> 4;

    f32x4 acc[4][4];
#pragma unroll
    for (int i = 0; i < 4; i++)
#pragma unroll
        for (int j = 0; j < 4; j++) acc[i][j] = (f32x4){0.f, 0.f, 0.f, 0.f};

    auto STAGE = [&](int buf, int kt) {
        int kof = kt * 32;
#pragma unroll
        for (int j = 0; j < 2; j++) {
            int seg = w * 2 + j;            // 0..7
            int r = seg * 16 + rsub;        // 0..127
            const u16* gA = Ab + (size_t)r * Cc_ + kof + csub * 8;
            __builtin_amdgcn_global_load_lds((const AS1 u32*)gA,
                                             (AS3 u32*)&lA[buf][seg * 512], 16, 0, 0);
            const u16* gB = Bb + (size_t)r * Cc_ + kof + csub * 8;
            __builtin_amdgcn_global_load_lds((const AS1 u32*)gB,
                                             (AS3 u32*)&lB[buf][seg * 512], 16, 0, 0);
        }
    };

    STAGE(0, 0);
    __syncthreads();            // drains vmcnt -> buf0 ready
    int cur = 0;
    for (int kt = 0; kt < 16; kt++) {
        if (kt < 15) STAGE(cur ^ 1, kt + 1);   // prefetch next tile first

        short8 aF[4], bF[4];
#pragma unroll
        for (int i = 0; i < 4; i++)
            aF[i] = *(const short8*)&lA[cur][(m_off + i * 16 + row_l) * 32 + quad * 8];
#pragma unroll
        for (int j = 0; j < 4; j++)
            bF[j] = *(const short8*)&lB[cur][(n_off + j * 16 + row_l) * 32 + quad * 8];

#pragma unroll
        for (int i = 0; i < 4; i++)
#pragma unroll
            for (int j = 0; j < 4; j++)
                acc[i][j] = __builtin_amdgcn_mfma_f32_16x16x32_bf16(aF[i], bF[j], acc[i][j], 0, 0, 0);

        __syncthreads();        // waits prefetch done + all reads of cur done
        cur ^= 1;
    }

#pragma unroll
    for (int i = 0; i < 4; i++) {
#pragma unroll
        for (int j = 0; j < 4; j++) {
            int gn = n_off + j * 16 + row_l;
            float bv = bias[tileN * 128 + gn];
#pragma unroll
            for (int r = 0; r < 4; r++) {
                int gm = m_off + i * 16 + quad * 4 + r;
                size_t idx = (size_t)b * Nn_ * Nn_ + (size_t)tileM * 128 * Nn_ +
                             (size_t)tileN * 128 + (size_t)gm * Nn_ + gn;
                Out[idx] = f2bf(acc[i][j][r] + bv);
            }
        }
    }
}

// ---------------------------------------------------------------------------
// Kernel 5: GEMM2 + fused LayerNorm, v2 (BM 64 -> 32).
// out[b][m][c] = LN_c( sum_n pw[b][m][n] * dT[b][c][n] ) * gamma + beta
// Tile: BM=32 rows x BN=512 (FULL C) x BK=32, 512 threads = 8 waves.
// 16 blocks/batch -> only 4 live batches per XCD -> dT panels (4x512KB=2MB)
// stay L2-resident; the per-step B staging becomes L2-broadcast instead of
// L3-thrash. LN fused in epilogue as before.
// ---------------------------------------------------------------------------
__global__ __launch_bounds__(512, 4) void gemm2_ln(const u16* __restrict__ A,
                                                   const u16* __restrict__ Bt,
                                                   float* __restrict__ out,
                                                   const float* __restrict__ gamma,
                                                   const float* __restrict__ beta) {
    __shared__ __align__(16) u16 lA[2][32 * 32];    // 2 KB each
    __shared__ __align__(16) u16 lB[2][512 * 32];   // 32 KB each -> 68 KB total

    // grid = 2048 = 8 XCDs x 256 slots; 16 consecutive slots = one batch
    int wg = blockIdx.x;
    int xcd = wg & 7, slot = wg >> 3;
    int b = xcd * 16 + (slot >> 4);
    int tm = slot & 15;                     // M-tile (32 rows)

    const u16* Ab = A + ((size_t)b * Nn_ + (size_t)tm * 32) * Nn_;
    const u16* Bb = Bt + (size_t)b * Cc_ * Nn_;

    int tid = threadIdx.x, w = tid >> 6, l = tid & 63;   // w: 0..7
    int rsub = l >> 2, csub = l & 3;
    int row_l = l & 15, quad = l >> 4;
    int n_off = w * 64;                     // wave's 64-col slice of C

    f32x4 acc[2][4];
#pragma unroll
    for (int i = 0; i < 2; i++)
#pragma unroll
        for (int j = 0; j < 4; j++) acc[i][j] = (f32x4){0.f, 0.f, 0.f, 0.f};

    auto STAGE = [&](int buf, int kt) {
        int kof = kt * 32;
#pragma unroll
        for (int j = 0; j < 4; j++) {
            int seg = w * 4 + j;            // 0..31 : Bt row-segments
            int r = seg * 16 + rsub;        // 0..511
            const u16* gB = Bb + (size_t)r * Nn_ + kof + csub * 8;
            __builtin_amdgcn_global_load_lds((const AS1 u32*)gB,
                                             (AS3 u32*)&lB[buf][seg * 512], 16, 0, 0);
        }
        if (w < 2) {                        // A: 2 segments of 16 rows
            int r = w * 16 + rsub;          // 0..31
            const u16* gA = Ab + (size_t)r * Nn_ + kof + csub * 8;
            __builtin_amdgcn_global_load_lds((const AS1 u32*)gA,
                                             (AS3 u32*)&lA[buf][w * 512], 16, 0, 0);
        }
    };

    STAGE(0, 0);
    __syncthreads();
    int cur = 0;
    for (int kt = 0; kt < 16; kt++) {
        if (kt < 15) STAGE(cur ^ 1, kt + 1);

        short8 aF[2], bF[4];
#pragma unroll
        for (int i = 0; i < 2; i++)
            aF[i] = *(const short8*)&lA[cur][(i * 16 + row_l) * 32 + quad * 8];
#pragma unroll
        for (int j = 0; j < 4; j++)
            bF[j] = *(const short8*)&lB[cur][(n_off + j * 16 + row_l) * 32 + quad * 8];

#pragma unroll
        for (int i = 0; i < 2; i++)
#pragma unroll
            for (int j = 0; j < 4; j++)
                acc[i][j] = __builtin_amdgcn_mfma_f32_16x16x32_bf16(aF[i], bF[j], acc[i][j], 0, 0, 0);

        __syncthreads();
        cur ^= 1;
    }

    // ---- fused LayerNorm epilogue ----
    // acc[i][j][r]: row = i*16 + quad*4 + r (0..31), col = n_off + j*16 + row_l
    float* red  = (float*)&lA[0][0];   // [8 waves][32 rows][2] = 2 KB (lA dead)
    float* musd = (float*)&lB[0][0];   // [32] mu, [32] rsigma   (lB dead)

#pragma unroll
    for (int i = 0; i < 2; i++) {
#pragma unroll
        for (int r = 0; r < 4; r++) {
            float a0 = acc[i][0][r], a1 = acc[i][1][r], a2 = acc[i][2][r], a3 = acc[i][3][r];
            float s  = a0 + a1 + a2 + a3;
            float ss = a0 * a0 + a1 * a1 + a2 * a2 + a3 * a3;
#pragma unroll
            for (int off = 8; off > 0; off >>= 1) {
                s  += __shfl_xor(s, off);
                ss += __shfl_xor(ss, off);
            }
            if (row_l == 0) {
                int row = i * 16 + quad * 4 + r;
                red[(w * 32 + row) * 2 + 0] = s;
                red[(w * 32 + row) * 2 + 1] = ss;
            }
        }
    }
    __syncthreads();
    if (w == 0 && l < 32) {     // lane l finalizes row l
        float s = 0.f, ss = 0.f;
#pragma unroll
        for (int ww = 0; ww < 8; ww++) {
            s  += red[(ww * 32 + l) * 2 + 0];
            ss += red[(ww * 32 + l) * 2 + 1];
        }
        float mu = s * (1.f / 512.f);
        float var = ss * (1.f / 512.f) - mu * mu;
        musd[l] = mu;
        musd[32 + l] = rsqrtf(var + 1e-5f);
    }
    __syncthreads();

    float* outb = out + ((size_t)b * Nn_ + (size_t)tm * 32) * Cc_;
    int gc0 = n_off + row_l;
    float gv[4], bv[4];
#pragma unroll
    for (int j = 0; j < 4; j++) {
        gv[j] = gamma[gc0 + j * 16];
        bv[j] = beta[gc0 + j * 16];
    }
#pragma unroll
    for (int i = 0; i < 2; i++) {
#pragma unroll
        for (int r = 0; r < 4; r++) {
            int row = i * 16 + quad * 4 + r;
            float mu = musd[row], rs = musd[32 + row];
#pragma unroll
            for (int j = 0; j < 4; j++)
                outb[(size_t)row * Cc_ + gc0 + j * 16] = (acc[i][j][r] - mu) * rs * gv[j] + bv[j];
        }
    }
}

// ---------------------------------------------------------------------------
extern "C" void kernel_launch(void* const* d_in, const int* in_sizes, int n_in,
                              void* d_out, int out_size, void* d_ws, size_t ws_size,
                              hipStream_t stream) {
    const float* q     = (const float*)d_in[0];
    const float* v     = (const float*)d_in[1];
    const float* W     = (const float*)d_in[2];
    const float* bl    = (const float*)d_in[3];
    const float* gamma = (const float*)d_in[4];
    const float* beta  = (const float*)d_in[5];

    char* ws = (char*)d_ws;
    u16*   WT  = (u16*)ws;                                 // 512*512*2      = 524288
    float* dw  = (float*)(ws + 524288);                    // 128*512*3*4    = 786432
    u16*   pw  = (u16*)(ws + 1310720);                     // 128*512*512*2  = 67108864
    u16*   dT  = (u16*)(ws + 68419584);                    // 128*512*512*2  = 67108864
    float* out = (float*)d_out;
    u16*   qbf = (u16*)d_out;   // scratch in d_out; dead before gemm2_ln writes

    prep_kernel<<<dim3((Bb_ * Nn_) / (4 * ROWS_PER_WAVE)), 256, 0, stream>>>(q, W, bl, qbf, dw);
    wt_kernel<<<dim3(2, 512), 256, 0, stream>>>(W, WT);
    depthT_kernel<<<dim3(8, 8, Bb_), 256, 0, stream>>>(v, dw, dT);

    // GEMM1: pw = qbf @ WT^T + bias   (bf16 out), 2048 swizzled blocks
    gemm1<<<dim3(2048), 256, 0, stream>>>(qbf, WT, pw, bl + 3);
    // GEMM2 + LN: out = LN(pw @ dT^T), 2048 swizzled blocks (BM=32), fp32 out
    gemm2_ln<<<dim3(2048), 512, 0, stream>>>(pw, dT, out, gamma, beta);
}

// Round 4
// 513.864 us; speedup vs baseline: 1.0766x; 1.0766x over previous
//
#include <hip/hip_runtime.h>
#include <hip/hip_bf16.h>

typedef unsigned short u16;
typedef unsigned int u32;
typedef __attribute__((ext_vector_type(8))) short short8;
typedef __attribute__((ext_vector_type(8))) unsigned short ushort8;
typedef __attribute__((ext_vector_type(4))) float f32x4;

#define AS1 __attribute__((address_space(1)))
#define AS3 __attribute__((address_space(3)))

#define Bb_ 128
#define Nn_ 512
#define Cc_ 512
#define NK_ 515

__device__ __forceinline__ u16 f2bf(float f) {
    union { float f; u32 i; } t; t.f = f;
    u32 x = t.i;
    u32 r = (x + 0x7fffu + ((x >> 16) & 1u)) >> 16;  // round-nearest-even
    return (u16)r;
}

// ---------------------------------------------------------------------------
// Kernel 1 (fused prep): per (b,n) row of fp32 query:
//   qbf[row][c] = bf16(q[row][c])
//   dw[row][j]  = sum_c q[row][c]*W[c][j] + b_lin[j]   (fp32, j=0..2)
// ---------------------------------------------------------------------------
#define ROWS_PER_WAVE 32
__global__ void prep_kernel(const float* __restrict__ q, const float* __restrict__ W,
                            const float* __restrict__ bl,
                            u16* __restrict__ qbf, float* __restrict__ dw) {
    __shared__ float wc[3][512];
    int tid = threadIdx.x;
    for (int idx = tid; idx < 3 * 512; idx += 256) {
        int j = idx >> 9, c = idx & 511;
        wc[j][c] = W[c * NK_ + j];
    }
    __syncthreads();

    int w = tid >> 6, l = tid & 63;
    int c0 = l * 8;
    float w0[8], w1[8], w2[8];
#pragma unroll
    for (int e = 0; e < 8; e++) {
        w0[e] = wc[0][c0 + e];
        w1[e] = wc[1][c0 + e];
        w2[e] = wc[2][c0 + e];
    }
    float bl0 = bl[0], bl1 = bl[1], bl2 = bl[2];

    size_t row0 = (size_t)blockIdx.x * (4 * ROWS_PER_WAVE) + (size_t)w * ROWS_PER_WAVE;
#pragma unroll 2
    for (int rr = 0; rr < ROWS_PER_WAVE; rr++) {
        size_t row = row0 + rr;
        const float* qr = q + row * Cc_;
        f32x4 x0 = *(const f32x4*)(qr + c0);
        f32x4 x1 = *(const f32x4*)(qr + c0 + 4);
        float xf[8] = {x0[0], x0[1], x0[2], x0[3], x1[0], x1[1], x1[2], x1[3]};
        ushort8 y;
        float s0 = 0.f, s1 = 0.f, s2 = 0.f;
#pragma unroll
        for (int e = 0; e < 8; e++) {
            float qf = xf[e];
            y[e] = f2bf(qf);
            s0 += qf * w0[e];
            s1 += qf * w1[e];
            s2 += qf * w2[e];
        }
        *(ushort8*)(qbf + row * Cc_ + c0) = y;
#pragma unroll
        for (int off = 32; off > 0; off >>= 1) {
            s0 += __shfl_xor(s0, off);
            s1 += __shfl_xor(s1, off);
            s2 += __shfl_xor(s2, off);
        }
        if (l == 0) {
            dw[row * 3 + 0] = s0 + bl0;
            dw[row * 3 + 1] = s1 + bl1;
            dw[row * 3 + 2] = s2 + bl2;
        }
    }
}

// ---------------------------------------------------------------------------
// Kernel 2: WT[n][c] = bf16(W_lin[c][n+3])   (512x512)
// ---------------------------------------------------------------------------
__global__ void wt_kernel(const float* __restrict__ W, u16* __restrict__ WT) {
    int n = blockIdx.y;
    int c = blockIdx.x * 256 + threadIdx.x;
    WT[n * Cc_ + c] = f2bf(W[c * NK_ + n + 3]);
}

// ---------------------------------------------------------------------------
// Kernel 3: depthT[b][c][n] = bf16(relu(dw0*v[c-1] + dw1*v[c] + dw2*v[c+1]))
// ---------------------------------------------------------------------------
__global__ void depthT_kernel(const float* __restrict__ val, const float* __restrict__ dw,
                              u16* __restrict__ dT) {
    __shared__ float vt[64][67];
    __shared__ float dws[64][3];
    int b = blockIdx.z;
    int c0 = blockIdx.x * 64;
    int n0 = blockIdx.y * 64;
    int tid = threadIdx.x;

    const float* vbase = val + ((size_t)b * Nn_ + n0) * Cc_;
    for (int idx = tid; idx < 64 * 66; idx += 256) {
        int r = idx / 66, cc = idx % 66;
        int c = c0 - 1 + cc;
        float x = 0.f;
        if (c >= 0 && c < Cc_) x = vbase[(size_t)r * Cc_ + c];
        vt[r][cc] = x;
    }
    if (tid < 192) {
        int r = tid / 3, j = tid % 3;
        dws[r][j] = dw[((size_t)b * Nn_ + n0 + r) * 3 + j];
    }
    __syncthreads();

    int nn = tid & 63;
    int ccb = tid >> 6;
    u16* out = dT + ((size_t)b * Cc_ + c0) * Nn_ + n0;
    float d0 = dws[nn][0], d1 = dws[nn][1], d2 = dws[nn][2];
#pragma unroll
    for (int p = 0; p < 16; p++) {
        int cc = ccb + p * 4;
        float x = d0 * vt[nn][cc] + d1 * vt[nn][cc + 1] + d2 * vt[nn][cc + 2];
        x = x > 0.f ? x : 0.f;
        out[(size_t)cc * Nn_ + nn] = f2bf(x);
    }
}

// ---------------------------------------------------------------------------
// Unified big-tile GEMM: BM=128 x BN=512(full) x BK=32, 512 threads = 8 waves,
// each wave owns a 128x64 slab (acc[8][4]). Double-buffered 2-phase prefetch,
// batch-pinned XCD swizzle. Staged bytes per block: 16 x (8KB A + 32KB B) =
// 640 KB for 128x512x512 MACs -> 1.8x fewer staged bytes than BM=64.
// LN=0: += bias[n], bf16 out.   LN=1: fused LayerNorm over C=512, fp32 out.
// strideB: per-batch B stride in elements (0 = shared panel, i.e. WT).
// ---------------------------------------------------------------------------
template <int LN>
__global__ __launch_bounds__(512, 2) void gemm_k(const u16* __restrict__ A,
                                                 const u16* __restrict__ Bt,
                                                 void* __restrict__ Outv,
                                                 const float* __restrict__ bias,
                                                 const float* __restrict__ gamma,
                                                 const float* __restrict__ beta,
                                                 long strideB) {
    __shared__ __align__(16) u16 lA[2][128 * 32];   // 8 KB each
    __shared__ __align__(16) u16 lB[2][512 * 32];   // 32 KB each -> 80 KB total

    // grid = 512 = 8 XCDs x 64 slots; 4 consecutive slots = one batch
    int wg = blockIdx.x;
    int xcd = wg & 7, slot = wg >> 3;
    int b = xcd * 16 + (slot >> 2);
    int tm = slot & 3;                      // M-tile (128 rows)

    const u16* Ab = A + ((size_t)b * Nn_ + (size_t)tm * 128) * 512;
    const u16* Bb = Bt + (size_t)b * strideB;

    int tid = threadIdx.x, w = tid >> 6, l = tid & 63;   // w: 0..7
    int rsub = l >> 2, csub = l & 3;
    int row_l = l & 15, quad = l >> 4;
    int n_off = w * 64;                     // wave's 64-col slice

    f32x4 acc[8][4];
#pragma unroll
    for (int i = 0; i < 8; i++)
#pragma unroll
        for (int j = 0; j < 4; j++) acc[i][j] = (f32x4){0.f, 0.f, 0.f, 0.f};

    auto STAGE = [&](int buf, int kt) {
        int kof = kt * 32;
#pragma unroll
        for (int j = 0; j < 4; j++) {
            int seg = w * 4 + j;            // 0..31 : B row-segments
            int r = seg * 16 + rsub;        // 0..511
            const u16* gB = Bb + (size_t)r * 512 + kof + csub * 8;
            __builtin_amdgcn_global_load_lds((const AS1 u32*)gB,
                                             (AS3 u32*)&lB[buf][seg * 512], 16, 0, 0);
        }
        {                                   // A: 8 segments of 16 rows, one per wave
            int r = w * 16 + rsub;          // 0..127
            const u16* gA = Ab + (size_t)r * 512 + kof + csub * 8;
            __builtin_amdgcn_global_load_lds((const AS1 u32*)gA,
                                             (AS3 u32*)&lA[buf][w * 512], 16, 0, 0);
        }
    };

    STAGE(0, 0);
    __syncthreads();            // drains vmcnt -> buf0 ready
    int cur = 0;
    for (int kt = 0; kt < 16; kt++) {
        if (kt < 15) STAGE(cur ^ 1, kt + 1);   // prefetch next K-tile first

        short8 aF[8], bF[4];
#pragma unroll
        for (int i = 0; i < 8; i++)
            aF[i] = *(const short8*)&lA[cur][(i * 16 + row_l) * 32 + quad * 8];
#pragma unroll
        for (int j = 0; j < 4; j++)
            bF[j] = *(const short8*)&lB[cur][(n_off + j * 16 + row_l) * 32 + quad * 8];

#pragma unroll
        for (int i = 0; i < 8; i++)
#pragma unroll
            for (int j = 0; j < 4; j++)
                acc[i][j] = __builtin_amdgcn_mfma_f32_16x16x32_bf16(aF[i], bF[j], acc[i][j], 0, 0, 0);

        __syncthreads();        // prefetch landed + all reads of cur done
        cur ^= 1;
    }

    if (!LN) {
        // bias + bf16 store
        u16* outb = (u16*)Outv + ((size_t)b * Nn_ + (size_t)tm * 128) * 512;
#pragma unroll
        for (int j = 0; j < 4; j++) {
            int gn = n_off + j * 16 + row_l;
            float bv = bias[gn];
#pragma unroll
            for (int i = 0; i < 8; i++) {
#pragma unroll
                for (int r = 0; r < 4; r++) {
                    int gm = i * 16 + quad * 4 + r;
                    outb[(size_t)gm * 512 + gn] = f2bf(acc[i][j][r] + bv);
                }
            }
        }
    } else {
        // ---- fused LayerNorm epilogue ----
        // acc[i][j][r]: row = i*16+quad*4+r (0..127), col = n_off+j*16+row_l
        float* red  = (float*)&lA[0][0];   // [8 waves][128 rows][2] = 8 KB (lA dead)
        float* musd = (float*)&lB[0][0];   // [128] mu, [128] rsigma (lB dead)

#pragma unroll
        for (int i = 0; i < 8; i++) {
#pragma unroll
            for (int r = 0; r < 4; r++) {
                float a0 = acc[i][0][r], a1 = acc[i][1][r], a2 = acc[i][2][r], a3 = acc[i][3][r];
                float s  = a0 + a1 + a2 + a3;
                float ss = a0 * a0 + a1 * a1 + a2 * a2 + a3 * a3;
#pragma unroll
                for (int off = 8; off > 0; off >>= 1) {
                    s  += __shfl_xor(s, off);
                    ss += __shfl_xor(ss, off);
                }
                if (row_l == 0) {
                    int row = i * 16 + quad * 4 + r;
                    red[(w * 128 + row) * 2 + 0] = s;
                    red[(w * 128 + row) * 2 + 1] = ss;
                }
            }
        }
        __syncthreads();
        if (tid < 128) {        // thread `tid` finalizes row `tid`
            float s = 0.f, ss = 0.f;
#pragma unroll
            for (int ww = 0; ww < 8; ww++) {
                s  += red[(ww * 128 + tid) * 2 + 0];
                ss += red[(ww * 128 + tid) * 2 + 1];
            }
            float mu = s * (1.f / 512.f);
            float var = ss * (1.f / 512.f) - mu * mu;
            musd[tid] = mu;
            musd[128 + tid] = rsqrtf(var + 1e-5f);
        }
        __syncthreads();

        float* outb = (float*)Outv + ((size_t)b * Nn_ + (size_t)tm * 128) * 512;
        int gc0 = n_off + row_l;
        float gv[4], bv[4];
#pragma unroll
        for (int j = 0; j < 4; j++) {
            gv[j] = gamma[gc0 + j * 16];
            bv[j] = beta[gc0 + j * 16];
        }
#pragma unroll
        for (int i = 0; i < 8; i++) {
#pragma unroll
            for (int r = 0; r < 4; r++) {
                int row = i * 16 + quad * 4 + r;
                float mu = musd[row], rs = musd[128 + row];
#pragma unroll
                for (int j = 0; j < 4; j++)
                    outb[(size_t)row * 512 + gc0 + j * 16] = (acc[i][j][r] - mu) * rs * gv[j] + bv[j];
            }
        }
    }
}

// ---------------------------------------------------------------------------
extern "C" void kernel_launch(void* const* d_in, const int* in_sizes, int n_in,
                              void* d_out, int out_size, void* d_ws, size_t ws_size,
                              hipStream_t stream) {
    const float* q     = (const float*)d_in[0];
    const float* v     = (const float*)d_in[1];
    const float* W     = (const float*)d_in[2];
    const float* bl    = (const float*)d_in[3];
    const float* gamma = (const float*)d_in[4];
    const float* beta  = (const float*)d_in[5];

    char* ws = (char*)d_ws;
    u16*   WT  = (u16*)ws;                                 // 512*512*2      = 524288
    float* dw  = (float*)(ws + 524288);                    // 128*512*3*4    = 786432
    u16*   pw  = (u16*)(ws + 1310720);                     // 128*512*512*2  = 67108864
    u16*   dT  = (u16*)(ws + 68419584);                    // 128*512*512*2  = 67108864
    float* out = (float*)d_out;
    u16*   qbf = (u16*)d_out;   // scratch in d_out; dead before gemm_k<1> writes

    prep_kernel<<<dim3((Bb_ * Nn_) / (4 * ROWS_PER_WAVE)), 256, 0, stream>>>(q, W, bl, qbf, dw);
    wt_kernel<<<dim3(2, 512), 256, 0, stream>>>(W, WT);
    depthT_kernel<<<dim3(8, 8, Bb_), 256, 0, stream>>>(v, dw, dT);

    // GEMM1: pw = qbf @ WT^T + bias (bf16 out); WT shared -> strideB = 0
    gemm_k<0><<<dim3(512), 512, 0, stream>>>(qbf, WT, pw, bl + 3, nullptr, nullptr, 0L);
    // GEMM2 + LN: out = LN(pw @ dT^T) (fp32 out); dT per-batch stride
    gemm_k<1><<<dim3(512), 512, 0, stream>>>(pw, dT, out, nullptr, gamma, beta,
                                             (long)Cc_ * Nn_);
}

// Round 6
// 503.783 us; speedup vs baseline: 1.0982x; 1.0200x over previous
//
#include <hip/hip_runtime.h>
#include <hip/hip_bf16.h>

typedef unsigned short u16;
typedef unsigned int u32;
typedef __attribute__((ext_vector_type(8))) short short8;
typedef __attribute__((ext_vector_type(8))) unsigned short ushort8;
typedef __attribute__((ext_vector_type(4))) float f32x4;

#define AS1 __attribute__((address_space(1)))
#define AS3 __attribute__((address_space(3)))

#define Bb_ 128
#define Nn_ 512
#define Cc_ 512
#define NK_ 515

__device__ __forceinline__ u16 f2bf(float f) {
    union { float f; u32 i; } t; t.f = f;
    u32 x = t.i;
    u32 r = (x + 0x7fffu + ((x >> 16) & 1u)) >> 16;  // round-nearest-even
    return (u16)r;
}

// ---------------------------------------------------------------------------
// Kernel 1 (fused prep): per (b,n) row of fp32 query:
//   qbf[row][c] = bf16(q[row][c])
//   dw[row][j]  = sum_c q[row][c]*W[c][j] + b_lin[j]   (fp32, j=0..2)
// ---------------------------------------------------------------------------
#define ROWS_PER_WAVE 32
__global__ void prep_kernel(const float* __restrict__ q, const float* __restrict__ W,
                            const float* __restrict__ bl,
                            u16* __restrict__ qbf, float* __restrict__ dw) {
    __shared__ float wc[3][512];
    int tid = threadIdx.x;
    for (int idx = tid; idx < 3 * 512; idx += 256) {
        int j = idx >> 9, c = idx & 511;
        wc[j][c] = W[c * NK_ + j];
    }
    __syncthreads();

    int w = tid >> 6, l = tid & 63;
    int c0 = l * 8;
    float w0[8], w1[8], w2[8];
#pragma unroll
    for (int e = 0; e < 8; e++) {
        w0[e] = wc[0][c0 + e];
        w1[e] = wc[1][c0 + e];
        w2[e] = wc[2][c0 + e];
    }
    float bl0 = bl[0], bl1 = bl[1], bl2 = bl[2];

    size_t row0 = (size_t)blockIdx.x * (4 * ROWS_PER_WAVE) + (size_t)w * ROWS_PER_WAVE;
#pragma unroll 2
    for (int rr = 0; rr < ROWS_PER_WAVE; rr++) {
        size_t row = row0 + rr;
        const float* qr = q + row * Cc_;
        f32x4 x0 = *(const f32x4*)(qr + c0);
        f32x4 x1 = *(const f32x4*)(qr + c0 + 4);
        float xf[8] = {x0[0], x0[1], x0[2], x0[3], x1[0], x1[1], x1[2], x1[3]};
        ushort8 y;
        float s0 = 0.f, s1 = 0.f, s2 = 0.f;
#pragma unroll
        for (int e = 0; e < 8; e++) {
            float qf = xf[e];
            y[e] = f2bf(qf);
            s0 += qf * w0[e];
            s1 += qf * w1[e];
            s2 += qf * w2[e];
        }
        *(ushort8*)(qbf + row * Cc_ + c0) = y;
#pragma unroll
        for (int off = 32; off > 0; off >>= 1) {
            s0 += __shfl_xor(s0, off);
            s1 += __shfl_xor(s1, off);
            s2 += __shfl_xor(s2, off);
        }
        if (l == 0) {
            dw[row * 3 + 0] = s0 + bl0;
            dw[row * 3 + 1] = s1 + bl1;
            dw[row * 3 + 2] = s2 + bl2;
        }
    }
}

// ---------------------------------------------------------------------------
// Kernel 2: WT[n][c] = bf16(W_lin[c][n+3])   (512x512)
// ---------------------------------------------------------------------------
__global__ void wt_kernel(const float* __restrict__ W, u16* __restrict__ WT) {
    int n = blockIdx.y;
    int c = blockIdx.x * 256 + threadIdx.x;
    WT[n * Cc_ + c] = f2bf(W[c * NK_ + n + 3]);
}

// ---------------------------------------------------------------------------
// Kernel 3: depthT[b][c][n] = bf16(relu(dw0*v[c-1] + dw1*v[c] + dw2*v[c+1]))
// v2: vectorized output — each lane produces 8 consecutive n for one c and
// stores ushort8 (16B/lane vs 2B/lane scatter before); conv weights for its
// 8 rows hoisted to 24 registers.
// ---------------------------------------------------------------------------
__global__ void depthT_kernel(const float* __restrict__ val, const float* __restrict__ dw,
                              u16* __restrict__ dT) {
    __shared__ float vt[64][67];
    __shared__ float dws[64][3];
    int b = blockIdx.z;
    int c0 = blockIdx.x * 64;
    int n0 = blockIdx.y * 64;
    int tid = threadIdx.x;

    const float* vbase = val + ((size_t)b * Nn_ + n0) * Cc_;
    for (int idx = tid; idx < 64 * 66; idx += 256) {
        int r = idx / 66, cc = idx % 66;
        int c = c0 - 1 + cc;
        float x = 0.f;
        if (c >= 0 && c < Cc_) x = vbase[(size_t)r * Cc_ + c];
        vt[r][cc] = x;
    }
    if (tid < 192) {
        int r = tid / 3, j = tid % 3;
        dws[r][j] = dw[((size_t)b * Nn_ + n0 + r) * 3 + j];
    }
    __syncthreads();

    int nn0 = (tid & 7) * 8;     // 8 consecutive n rows owned by this lane
    int ccx = tid >> 3;          // 0..31 : c within tile (two halves)
    float d0[8], d1[8], d2[8];
#pragma unroll
    for (int e = 0; e < 8; e++) {
        d0[e] = dws[nn0 + e][0];
        d1[e] = dws[nn0 + e][1];
        d2[e] = dws[nn0 + e][2];
    }
    u16* out = dT + ((size_t)b * Cc_ + c0) * Nn_ + n0;
#pragma unroll
    for (int h = 0; h < 2; h++) {
        int cc = ccx + h * 32;
        ushort8 y;
#pragma unroll
        for (int e = 0; e < 8; e++) {
            float x = d0[e] * vt[nn0 + e][cc] + d1[e] * vt[nn0 + e][cc + 1] +
                      d2[e] * vt[nn0 + e][cc + 2];
            y[e] = f2bf(x > 0.f ? x : 0.f);
        }
        *(ushort8*)(out + (size_t)cc * Nn_ + nn0) = y;
    }
}

// ---------------------------------------------------------------------------
// Unified big-tile GEMM, v2: BM=128 x BN=512(full) x BK=32, 512 thr = 8 waves,
// wave owns 128x64 slab (acc[8][4]). T4 counted-vmcnt depth-2 pipeline:
// 3 LDS buffers (120 KB), one raw s_barrier per K-step, vmcnt(5) steady
// (tile t+1's 5 loads stay in flight across the barrier), never vmcnt(0)
// in the main loop. STAGE(t+2) issued right after the barrier.
// LN=0: += bias[n], bf16 out.   LN=1: fused LayerNorm over C=512, fp32 out.
// strideB: per-batch B stride in elements (0 = shared panel, i.e. WT).
// ---------------------------------------------------------------------------
template <int LN>
__global__ __launch_bounds__(512, 2) void gemm_k(const u16* __restrict__ A,
                                                 const u16* __restrict__ Bt,
                                                 void* __restrict__ Outv,
                                                 const float* __restrict__ bias,
                                                 const float* __restrict__ gamma,
                                                 const float* __restrict__ beta,
                                                 long strideB) {
    __shared__ __align__(16) u16 lA[3][128 * 32];   // 8 KB each
    __shared__ __align__(16) u16 lB[3][512 * 32];   // 32 KB each -> 120 KB total

    // grid = 512 = 8 XCDs x 64 slots; 4 consecutive slots = one batch
    int wg = blockIdx.x;
    int xcd = wg & 7, slot = wg >> 3;
    int b = xcd * 16 + (slot >> 2);
    int tm = slot & 3;                      // M-tile (128 rows)

    const u16* Ab = A + ((size_t)b * Nn_ + (size_t)tm * 128) * 512;
    const u16* Bb = Bt + (size_t)b * strideB;

    int tid = threadIdx.x, w = tid >> 6, l = tid & 63;   // w: 0..7
    int rsub = l >> 2, csub = l & 3;
    int row_l = l & 15, quad = l >> 4;
    int n_off = w * 64;                     // wave's 64-col slice

    f32x4 acc[8][4];
#pragma unroll
    for (int i = 0; i < 8; i++)
#pragma unroll
        for (int j = 0; j < 4; j++) acc[i][j] = (f32x4){0.f, 0.f, 0.f, 0.f};

    // 5 global_load_lds per lane per tile (4 B-segments + 1 A-segment)
    auto STAGE = [&](int buf, int kt) {
        int kof = kt * 32;
#pragma unroll
        for (int j = 0; j < 4; j++) {
            int seg = w * 4 + j;            // 0..31 : B row-segments
            int r = seg * 16 + rsub;        // 0..511
            const u16* gB = Bb + (size_t)r * 512 + kof + csub * 8;
            __builtin_amdgcn_global_load_lds((const AS1 u32*)gB,
                                             (AS3 u32*)&lB[buf][seg * 512], 16, 0, 0);
        }
        {                                   // A: 8 segments of 16 rows, one per wave
            int r = w * 16 + rsub;          // 0..127
            const u16* gA = Ab + (size_t)r * 512 + kof + csub * 8;
            __builtin_amdgcn_global_load_lds((const AS1 u32*)gA,
                                             (AS3 u32*)&lA[buf][w * 512], 16, 0, 0);
        }
    };

    STAGE(0, 0);
    STAGE(1, 1);
    for (int kt = 0; kt < 16; kt++) {
        // my tile-kt loads complete; tile-(kt+1)'s 5 may stay in flight
        if (kt < 15) asm volatile("s_waitcnt vmcnt(5)" ::: "memory");
        else         asm volatile("s_waitcnt vmcnt(0)" ::: "memory");
        __builtin_amdgcn_s_barrier();            // all waves' tile-kt loads done
        __builtin_amdgcn_sched_barrier(0);       // pin: no ds_read hoists above

        if (kt < 14) {
            int sb = kt + 2;
            STAGE(sb - (sb >= 3 ? 3 : 0) - (sb >= 6 ? 3 : 0) - (sb >= 9 ? 3 : 0) -
                      (sb >= 12 ? 3 : 0) - (sb >= 15 ? 3 : 0), sb);
        }

        int cur = kt % 3;
        short8 aF[8], bF[4];
#pragma unroll
        for (int i = 0; i < 8; i++)
            aF[i] = *(const short8*)&lA[cur][(i * 16 + row_l) * 32 + quad * 8];
#pragma unroll
        for (int j = 0; j < 4; j++)
            bF[j] = *(const short8*)&lB[cur][(n_off + j * 16 + row_l) * 32 + quad * 8];

#pragma unroll
        for (int i = 0; i < 8; i++)
#pragma unroll
            for (int j = 0; j < 4; j++)
                acc[i][j] = __builtin_amdgcn_mfma_f32_16x16x32_bf16(aF[i], bF[j], acc[i][j], 0, 0, 0);
    }
    __syncthreads();    // full drain once; epilogue reuses LDS as scratch

    if (!LN) {
        // bias + bf16 store
        u16* outb = (u16*)Outv + ((size_t)b * Nn_ + (size_t)tm * 128) * 512;
#pragma unroll
        for (int j = 0; j < 4; j++) {
            int gn = n_off + j * 16 + row_l;
            float bv = bias[gn];
#pragma unroll
            for (int i = 0; i < 8; i++) {
#pragma unroll
                for (int r = 0; r < 4; r++) {
                    int gm = i * 16 + quad * 4 + r;
                    outb[(size_t)gm * 512 + gn] = f2bf(acc[i][j][r] + bv);
                }
            }
        }
    } else {
        // ---- fused LayerNorm epilogue ----
        // acc[i][j][r]: row = i*16+quad*4+r (0..127), col = n_off+j*16+row_l
        float* red  = (float*)&lA[0][0];   // [8 waves][128 rows][2] = 8 KB (lA dead)
        float* musd = (float*)&lB[0][0];   // [128] mu, [128] rsigma (lB dead)

#pragma unroll
        for (int i = 0; i < 8; i++) {
#pragma unroll
            for (int r = 0; r < 4; r++) {
                float a0 = acc[i][0][r], a1 = acc[i][1][r], a2 = acc[i][2][r], a3 = acc[i][3][r];
                float s  = a0 + a1 + a2 + a3;
                float ss = a0 * a0 + a1 * a1 + a2 * a2 + a3 * a3;
#pragma unroll
                for (int off = 8; off > 0; off >>= 1) {
                    s  += __shfl_xor(s, off);
                    ss += __shfl_xor(ss, off);
                }
                if (row_l == 0) {
                    int row = i * 16 + quad * 4 + r;
                    red[(w * 128 + row) * 2 + 0] = s;
                    red[(w * 128 + row) * 2 + 1] = ss;
                }
            }
        }
        __syncthreads();
        if (tid < 128) {        // thread `tid` finalizes row `tid`
            float s = 0.f, ss = 0.f;
#pragma unroll
            for (int ww = 0; ww < 8; ww++) {
                s  += red[(ww * 128 + tid) * 2 + 0];
                ss += red[(ww * 128 + tid) * 2 + 1];
            }
            float mu = s * (1.f / 512.f);
            float var = ss * (1.f / 512.f) - mu * mu;
            musd[tid] = mu;
            musd[128 + tid] = rsqrtf(var + 1e-5f);
        }
        __syncthreads();

        float* outb = (float*)Outv + ((size_t)b * Nn_ + (size_t)tm * 128) * 512;
        int gc0 = n_off + row_l;
        float gv[4], bv[4];
#pragma unroll
        for (int j = 0; j < 4; j++) {
            gv[j] = gamma[gc0 + j * 16];
            bv[j] = beta[gc0 + j * 16];
        }
#pragma unroll
        for (int i = 0; i < 8; i++) {
#pragma unroll
            for (int r = 0; r < 4; r++) {
                int row = i * 16 + quad * 4 + r;
                float mu = musd[row], rs = musd[128 + row];
#pragma unroll
                for (int j = 0; j < 4; j++)
                    outb[(size_t)row * 512 + gc0 + j * 16] = (acc[i][j][r] - mu) * rs * gv[j] + bv[j];
            }
        }
    }
}

// ---------------------------------------------------------------------------
extern "C" void kernel_launch(void* const* d_in, const int* in_sizes, int n_in,
                              void* d_out, int out_size, void* d_ws, size_t ws_size,
                              hipStream_t stream) {
    const float* q     = (const float*)d_in[0];
    const float* v     = (const float*)d_in[1];
    const float* W     = (const float*)d_in[2];
    const float* bl    = (const float*)d_in[3];
    const float* gamma = (const float*)d_in[4];
    const float* beta  = (const float*)d_in[5];

    char* ws = (char*)d_ws;
    u16*   WT  = (u16*)ws;                                 // 512*512*2      = 524288
    float* dw  = (float*)(ws + 524288);                    // 128*512*3*4    = 786432
    u16*   pw  = (u16*)(ws + 1310720);                     // 128*512*512*2  = 67108864
    u16*   dT  = (u16*)(ws + 68419584);                    // 128*512*512*2  = 67108864
    float* out = (float*)d_out;
    u16*   qbf = (u16*)d_out;   // scratch in d_out; dead before gemm_k<1> writes

    prep_kernel<<<dim3((Bb_ * Nn_) / (4 * ROWS_PER_WAVE)), 256, 0, stream>>>(q, W, bl, qbf, dw);
    wt_kernel<<<dim3(2, 512), 256, 0, stream>>>(W, WT);
    depthT_kernel<<<dim3(8, 8, Bb_), 256, 0, stream>>>(v, dw, dT);

    // GEMM1: pw = qbf @ WT^T + bias (bf16 out); WT shared -> strideB = 0
    gemm_k<0><<<dim3(512), 512, 0, stream>>>(qbf, WT, pw, bl + 3, nullptr, nullptr, 0L);
    // GEMM2 + LN: out = LN(pw @ dT^T) (fp32 out); dT per-batch stride
    gemm_k<1><<<dim3(512), 512, 0, stream>>>(pw, dT, out, nullptr, gamma, beta,
                                             (long)Cc_ * Nn_);
}